// Round 9
// baseline (262.785 us; speedup 1.0000x reference)
//
#include <hip/hip_runtime.h>

static inline int ceil_div(int a, int b){ return (a+b-1)/b; }
static inline size_t align_up(size_t x, size_t a){ return (x + a - 1) / a * a; }

typedef __bf16 bf16x8 __attribute__((ext_vector_type(8)));
typedef float  f32x4  __attribute__((ext_vector_type(4)));

static __device__ inline unsigned short f2bf(float f){
    unsigned int u = __float_as_uint(f);
    unsigned int lsb = (u >> 16) & 1u;
    u += 0x7FFFu + lsb;
    return (unsigned short)(u >> 16);
}
static __device__ inline float bf2f(unsigned short b){
    return __uint_as_float(((unsigned int)b) << 16);
}
static __device__ inline unsigned int packbf(float a, float b){
    return (unsigned int)f2bf(a) | ((unsigned int)f2bf(b) << 16);
}

// async 16B global->LDS (wave-uniform LDS base + lane*16 layout)
static __device__ inline void gload_lds16(const void* g, void* l) {
    __builtin_amdgcn_global_load_lds(
        (const __attribute__((address_space(1))) unsigned int*)g,
        (__attribute__((address_space(3))) unsigned int*)l, 16, 0, 0);
}

// Bt[o][kk] bf16: kk<1024 -> W[r=kk>>7][i=kk&127][o]; kk>=1024 -> root[kk-1024][o]
__global__ void compute_Bt_kernel(const float* __restrict__ comp, const float* __restrict__ basis,
                                  const float* __restrict__ root, unsigned short* __restrict__ Bt,
                                  int B) {
    int idx = blockIdx.x*blockDim.x + threadIdx.x;
    if (idx >= 128*1152) return;
    int o = idx / 1152, kk = idx - o*1152;
    float val;
    if (kk < 1024) {
        int r = kk >> 7, i = kk & 127;
        val = 0.f;
        for (int b = 0; b < B; ++b)
            val += comp[r*B+b] * basis[((size_t)b*128 + i)*128 + o];
    } else {
        val = root[(size_t)(kk-1024)*128 + o];
    }
    Bt[idx] = f2bf(val);
}

__global__ void count_kernel(const int* __restrict__ dst, const int* __restrict__ et,
                             int* __restrict__ cnt, int E, int R) {
    int e = blockIdx.x*blockDim.x + threadIdx.x;
    if (e >= E) return;
    atomicAdd(&cnt[(size_t)dst[e]*R + et[e]], 1);
}

__global__ __launch_bounds__(256)
void scan_block_kernel(const int* __restrict__ in, int* __restrict__ out,
                       int* __restrict__ bsums, int n) {
    __shared__ int tsum[256];
    int t = threadIdx.x;
    int idx0 = blockIdx.x*1024 + t*4;
    int v0 = (idx0+0 < n) ? in[idx0+0] : 0;
    int v1 = (idx0+1 < n) ? in[idx0+1] : 0;
    int v2 = (idx0+2 < n) ? in[idx0+2] : 0;
    int v3 = (idx0+3 < n) ? in[idx0+3] : 0;
    int s = v0+v1+v2+v3;
    tsum[t] = s; __syncthreads();
    for (int off = 1; off < 256; off <<= 1) {
        int x = (t >= off) ? tsum[t-off] : 0;
        __syncthreads();
        tsum[t] += x;
        __syncthreads();
    }
    int run = tsum[t] - s;
    if (idx0+0 < n) out[idx0+0] = run; run += v0;
    if (idx0+1 < n) out[idx0+1] = run; run += v1;
    if (idx0+2 < n) out[idx0+2] = run; run += v2;
    if (idx0+3 < n) out[idx0+3] = run;
    if (bsums && t == 255) bsums[blockIdx.x] = tsum[255];
}

__global__ void scan_add_kernel(int* __restrict__ out, const int* __restrict__ bs,
                                int n, int total) {
    int i = blockIdx.x*blockDim.x + threadIdx.x;
    if (i < n) out[i] += bs[i >> 10];
    if (i == 0) out[n] = total;
}

// slot = atomicAdd(&offsets[bin],1): offsets mutates into shifted-by-one bounds.
__global__ void fill_kernel(const int* __restrict__ src, const int* __restrict__ dst,
                            const int* __restrict__ et, int* __restrict__ offsets,
                            int* __restrict__ slot_src, int E, int R) {
    int e = blockIdx.x*blockDim.x + threadIdx.x;
    if (e >= E) return;
    int bin = dst[e]*R + et[e];
    int slot = atomicAdd(&offsets[bin], 1);
    slot_src[slot] = src[e];
}

// x (f32) -> compact bf16 buffer Xb [N][128] (u32 pairs)
__global__ __launch_bounds__(256)
void xb_kernel(const float* __restrict__ x, unsigned int* __restrict__ Xb2, int N) {
    int t = blockIdx.x*blockDim.x + threadIdx.x;
    int n = t >> 6;
    if (n >= N) return;
    int l = t & 63;
    float2 v = reinterpret_cast<const float2*>(x + (size_t)n*128)[l];
    Xb2[(size_t)n*64 + l] = packbf(v.x, v.y);
}

// Fused aggregate+GEMM: h(bf16)[Mpad][128] = relu( [means(Xb)|Xb] @ Bt^T + bias )
// Per block: 64 rows x 128 cols, 18 k-chunks of 64. Chunk t<16 = (rel=t>>1, half=t&1):
// A-tile computed IN-KERNEL by gathering bin edges from Xb (masked batch-4, 8 nodes
// in flight per wave) and ds_writing swizzled means. Chunks 16,17: Xb via gload_lds.
// B always via gload_lds. Bin b = [off[b-1], off[b]) with off[-1]=0 (post-fill conv).
__global__ __launch_bounds__(256)
void fused_gemm_kernel(const int* __restrict__ offsets, const int* __restrict__ slot_src,
                       const unsigned short* __restrict__ Xb,
                       const unsigned short* __restrict__ Btc,
                       const float* __restrict__ bias,
                       unsigned short* __restrict__ h, int NR_total) {
    __shared__ char ldsA[64*128];     // 8 KB
    __shared__ char ldsB[128*128];    // 16 KB
    __shared__ int  lds_off[513];     // bounds offsets[m0*8-1 .. m0*8+511]

    int tid  = threadIdx.x;
    int lane = tid & 63;
    int wid  = tid >> 6;
    int rg = wid & 1, cg = wid >> 1;
    int fr = lane & 15, kb = lane >> 4;
    long m0 = (long)blockIdx.x * 64;

    int lrow8 = lane >> 3;            // 0..7 row within a gload issue
    int lcb   = (lane & 7) * 16;      // 16B slot within 128B row
    int np = lane >> 5;               // half-wave: which node of the pair
    int fl = lane & 31;               // feature u32 within half (32 u32 = 64 bf16)

    const unsigned int* Xb2 = (const unsigned int*)Xb;

    // block-wide bin bounds into LDS
    for (int k = tid; k < 513; k += 256) {
        long gidx = m0*8 - 1 + k;
        int v = 0;
        if (gidx >= 0) {
            long ci = gidx < (long)NR_total ? gidx : (long)NR_total;
            v = offsets[ci];
        }
        lds_off[k] = v;
    }

    f32x4 acc[2][4];
    #pragma unroll
    for (int mf = 0; mf < 2; ++mf)
        #pragma unroll
        for (int nf = 0; nf < 4; ++nf) acc[mf][nf] = f32x4{0.f,0.f,0.f,0.f};

    const char* XbB = (const char*)Xb;
    const char* BtB = (const char*)Btc;

    __syncthreads();   // lds_off ready

    for (int t = 0; t < 18; ++t) {
        // ---- B stage (async, all chunks): 4 issues/wave ----
        #pragma unroll
        for (int i = 0; i < 4; ++i) {
            int col = wid*32 + i*8 + lrow8;
            int sw  = lcb ^ ((col & 7) << 4);
            const char* g = BtB + (size_t)col*2304 + t*128 + sw;
            gload_lds16(g, &ldsB[wid*4096 + i*1024 + lane*16]);
        }
        // ---- A stage ----
        if (t < 16) {
            int r = t >> 1, fh = t & 1;
            #pragma unroll
            for (int pg = 0; pg < 2; ++pg) {
                int lo[4], hi[4], sl[4][4];
                #pragma unroll
                for (int p4 = 0; p4 < 4; ++p4) {
                    int nl = wid*16 + (pg*4 + p4)*2 + np;
                    int bx = nl*8 + r;
                    lo[p4] = lds_off[bx];
                    hi[p4] = lds_off[bx+1];
                    #pragma unroll
                    for (int j = 0; j < 4; ++j) {
                        int idx = lo[p4] + j;
                        idx = idx < hi[p4]-1 ? idx : hi[p4]-1;
                        idx = idx > 0 ? idx : 0;
                        sl[p4][j] = slot_src[idx];
                    }
                }
                unsigned int uv[4][4];
                #pragma unroll
                for (int p4 = 0; p4 < 4; ++p4)
                    #pragma unroll
                    for (int j = 0; j < 4; ++j)
                        uv[p4][j] = Xb2[(size_t)sl[p4][j]*64 + fh*32 + fl];
                #pragma unroll
                for (int p4 = 0; p4 < 4; ++p4) {
                    int nl = wid*16 + (pg*4 + p4)*2 + np;
                    float ax = 0.f, ay = 0.f;
                    #pragma unroll
                    for (int j = 0; j < 4; ++j) {
                        unsigned int u = (lo[p4] + j < hi[p4]) ? uv[p4][j] : 0u;
                        ax += bf2f((unsigned short)(u & 0xFFFFu));
                        ay += bf2f((unsigned short)(u >> 16));
                    }
                    for (int e = lo[p4] + 4; e < hi[p4]; ++e) {   // rare tail
                        int s = slot_src[e];
                        unsigned int u = Xb2[(size_t)s*64 + fh*32 + fl];
                        ax += bf2f((unsigned short)(u & 0xFFFFu));
                        ay += bf2f((unsigned short)(u >> 16));
                    }
                    float inv = 1.f / fmaxf((float)(hi[p4]-lo[p4]), 1.f);
                    int byte = nl*128 + ((fl*4) ^ ((nl & 7) << 4));
                    *(unsigned int*)&ldsA[byte] = packbf(ax*inv, ay*inv);
                }
            }
        } else {
            #pragma unroll
            for (int i = 0; i < 2; ++i) {
                int row = wid*16 + i*8 + lrow8;
                int sw  = lcb ^ ((row & 7) << 4);
                const char* g = XbB + (size_t)(m0 + row)*256 + (t-16)*128 + sw;
                gload_lds16(g, &ldsA[wid*2048 + i*1024 + lane*16]);
            }
        }
        __syncthreads();   // drains vmcnt + lgkm -> LDS tile complete

        // ---- compute: 12 ds_read_b128 + 16 MFMA ----
        bf16x8 af[2][2], bfr[4][2];
        #pragma unroll
        for (int mf = 0; mf < 2; ++mf) {
            int row = rg*32 + mf*16 + fr;
            #pragma unroll
            for (int kk = 0; kk < 2; ++kk) {
                int byte = row*128 + ((kk*64 + kb*16) ^ ((row & 7) << 4));
                af[mf][kk] = *reinterpret_cast<const bf16x8*>(&ldsA[byte]);
            }
        }
        #pragma unroll
        for (int nf = 0; nf < 4; ++nf) {
            int col = cg*64 + nf*16 + fr;
            #pragma unroll
            for (int kk = 0; kk < 2; ++kk) {
                int byte = col*128 + ((kk*64 + kb*16) ^ ((col & 7) << 4));
                bfr[nf][kk] = *reinterpret_cast<const bf16x8*>(&ldsB[byte]);
            }
        }
        #pragma unroll
        for (int kk = 0; kk < 2; ++kk)
            #pragma unroll
            for (int mf = 0; mf < 2; ++mf)
                #pragma unroll
                for (int nf = 0; nf < 4; ++nf)
                    acc[mf][nf] = __builtin_amdgcn_mfma_f32_16x16x32_bf16(
                        af[mf][kk], bfr[nf][kk], acc[mf][nf], 0, 0, 0);
        __syncthreads();   // buffers safe to overwrite
    }

    float bb[4];
    #pragma unroll
    for (int nf = 0; nf < 4; ++nf) bb[nf] = bias[cg*64 + nf*16 + fr];

    #pragma unroll
    for (int mf = 0; mf < 2; ++mf)
        #pragma unroll
        for (int q = 0; q < 4; ++q) {
            long r = m0 + rg*32 + mf*16 + kb*4 + q;
            unsigned short* hr = h + (size_t)r*128 + cg*64;
            #pragma unroll
            for (int nf = 0; nf < 4; ++nf)
                hr[nf*16 + fr] = f2bf(fmaxf(acc[mf][nf][q] + bb[nf], 0.f));
        }
}

// Fused: per-graph row-range (binary search on sorted batch) -> mean pool -> FC.
__global__ __launch_bounds__(512)
void pool_fc_kernel(const unsigned int* __restrict__ h2, const int* __restrict__ batch,
                    const float* __restrict__ fw, const float* __restrict__ fb,
                    float* __restrict__ out, int N, int C) {
    int g = blockIdx.x;
    int t = threadIdx.x;
    int lo = 0, hi = N;
    while (lo < hi) { int mid = (lo+hi) >> 1; if (batch[mid] < g) lo = mid+1; else hi = mid; }
    int s0 = lo;
    hi = N;
    while (lo < hi) { int mid = (lo+hi) >> 1; if (batch[mid] < g+1) lo = mid+1; else hi = mid; }
    int s1 = lo;

    int d2 = t & 63;
    float ax = 0.f, ay = 0.f;
    for (int row = s0 + (t >> 6); row < s1; row += 8) {
        unsigned int u = h2[(size_t)row*64 + d2];
        ax += bf2f((unsigned short)(u & 0xFFFFu));
        ay += bf2f((unsigned short)(u >> 16));
    }
    __shared__ float ps[128];
    if (t < 128) ps[t] = 0.f;
    __syncthreads();
    atomicAdd(&ps[2*d2],   ax);
    atomicAdd(&ps[2*d2+1], ay);
    __syncthreads();
    if (t < C) {
        float inv = 1.f / fmaxf((float)(s1 - s0), 1.f);
        float s = 0.f;
        #pragma unroll 4
        for (int k = 0; k < 128; ++k) s += ps[k] * fw[(size_t)k*C + t];
        out[(size_t)g*C + t] = s * inv + fb[t];
    }
}

extern "C" void kernel_launch(void* const* d_in, const int* in_sizes, int n_in,
                              void* d_out, int out_size, void* d_ws, size_t ws_size,
                              hipStream_t stream) {
    const float* x       = (const float*)d_in[0];
    const int*   eindex  = (const int*)  d_in[1];
    const int*   etype   = (const int*)  d_in[2];
    const int*   batch   = (const int*)  d_in[4];
    const float* basis   = (const float*)d_in[6];
    const float* comp    = (const float*)d_in[7];
    const float* root    = (const float*)d_in[8];
    const float* bias    = (const float*)d_in[9];
    const float* fc_w    = (const float*)d_in[10];
    const float* fc_b    = (const float*)d_in[11];

    int N  = in_sizes[4];          // 50000
    int E  = in_sizes[2];          // 600000
    int C  = in_sizes[11];         // 16
    int G  = out_size / C;         // 64
    int IO = in_sizes[8];          // 16384
    int B  = in_sizes[6] / IO;     // 4
    int R  = in_sizes[7] / B;      // 8
    int NR = N * R;
    int MB = ceil_div(N, 64);      // 64-row GEMM blocks
    int Mpad = MB * 64;

    const int* src = eindex;
    const int* dst = eindex + E;

    // ---- workspace layout (~32 MB) ----
    char* base = (char*)d_ws;
    size_t off = 0;
    auto alloc = [&](size_t bytes) -> char* {
        char* p = base + off;
        off = align_up(off + bytes, 256);
        return p;
    };
    unsigned short* Bt  = (unsigned short*)alloc(sizeof(unsigned short)*128*1152);
    int*   cnt      = (int*)  alloc(sizeof(int)*(size_t)NR);
    int*   offsets  = (int*)  alloc(sizeof(int)*((size_t)NR+1));
    int*   bsums    = (int*)  alloc(sizeof(int)*1024);
    int*   slot_src = (int*)  alloc(sizeof(int)*(size_t)E);
    unsigned short* h  = (unsigned short*)alloc(sizeof(unsigned short)*(size_t)Mpad*128);
    unsigned short* Xb = (unsigned short*)alloc(sizeof(unsigned short)*(size_t)Mpad*128);

    // ---- pipeline ----
    hipMemsetAsync(cnt, 0, sizeof(int)*(size_t)NR, stream);
    compute_Bt_kernel<<<ceil_div(128*1152,256),256,0,stream>>>(comp, basis, root, Bt, B);
    count_kernel<<<ceil_div(E,256),256,0,stream>>>(dst, etype, cnt, E, R);

    int nb = ceil_div(NR, 1024);
    scan_block_kernel<<<nb,256,0,stream>>>(cnt, offsets, bsums, NR);
    scan_block_kernel<<<1,256,0,stream>>>(bsums, bsums, nullptr, nb);
    scan_add_kernel<<<ceil_div(NR,256),256,0,stream>>>(offsets, bsums, NR, E);

    fill_kernel<<<ceil_div(E,256),256,0,stream>>>(src, dst, etype, offsets, slot_src, E, R);

    xb_kernel<<<ceil_div(N*64,256),256,0,stream>>>(x, (unsigned int*)Xb, N);

    fused_gemm_kernel<<<MB,256,0,stream>>>(offsets, slot_src, Xb, Bt, bias, h, NR);

    pool_fc_kernel<<<G,512,0,stream>>>((const unsigned int*)h, batch, fc_w, fc_b,
                                       (float*)d_out, N, C);
}

// Round 10
// 217.430 us; speedup vs baseline: 1.2086x; 1.2086x over previous
//
#include <hip/hip_runtime.h>

static inline int ceil_div(int a, int b){ return (a+b-1)/b; }
static inline size_t align_up(size_t x, size_t a){ return (x + a - 1) / a * a; }

typedef __bf16 bf16x8 __attribute__((ext_vector_type(8)));
typedef float  f32x4  __attribute__((ext_vector_type(4)));

static __device__ inline unsigned short f2bf(float f){
    unsigned int u = __float_as_uint(f);
    unsigned int lsb = (u >> 16) & 1u;
    u += 0x7FFFu + lsb;
    return (unsigned short)(u >> 16);
}
static __device__ inline float bf2f(unsigned short b){
    return __uint_as_float(((unsigned int)b) << 16);
}
static __device__ inline unsigned int packbf(float a, float b){
    return (unsigned int)f2bf(a) | ((unsigned int)f2bf(b) << 16);
}

// async 16B global->LDS (wave-uniform LDS base + lane*16 layout)
static __device__ inline void gload_lds16(const void* g, void* l) {
    __builtin_amdgcn_global_load_lds(
        (const __attribute__((address_space(1))) unsigned int*)g,
        (__attribute__((address_space(3))) unsigned int*)l, 16, 0, 0);
}

// Bt[o][kk] bf16: kk<1024 -> W[r=kk>>7][i=kk&127][o]; kk>=1024 -> root[kk-1024][o]
__global__ void compute_Bt_kernel(const float* __restrict__ comp, const float* __restrict__ basis,
                                  const float* __restrict__ root, unsigned short* __restrict__ Bt,
                                  int B) {
    int idx = blockIdx.x*blockDim.x + threadIdx.x;
    if (idx >= 128*1152) return;
    int o = idx / 1152, kk = idx - o*1152;
    float val;
    if (kk < 1024) {
        int r = kk >> 7, i = kk & 127;
        val = 0.f;
        for (int b = 0; b < B; ++b)
            val += comp[r*B+b] * basis[((size_t)b*128 + i)*128 + o];
    } else {
        val = root[(size_t)(kk-1024)*128 + o];
    }
    Bt[idx] = f2bf(val);
}

__global__ void count_kernel(const int* __restrict__ dst, const int* __restrict__ et,
                             int* __restrict__ cnt, int E, int R) {
    int e = blockIdx.x*blockDim.x + threadIdx.x;
    if (e >= E) return;
    atomicAdd(&cnt[(size_t)dst[e]*R + et[e]], 1);
}

__global__ __launch_bounds__(256)
void scan_block_kernel(const int* __restrict__ in, int* __restrict__ out,
                       int* __restrict__ bsums, int n) {
    __shared__ int tsum[256];
    int t = threadIdx.x;
    int idx0 = blockIdx.x*1024 + t*4;
    int v0 = (idx0+0 < n) ? in[idx0+0] : 0;
    int v1 = (idx0+1 < n) ? in[idx0+1] : 0;
    int v2 = (idx0+2 < n) ? in[idx0+2] : 0;
    int v3 = (idx0+3 < n) ? in[idx0+3] : 0;
    int s = v0+v1+v2+v3;
    tsum[t] = s; __syncthreads();
    for (int off = 1; off < 256; off <<= 1) {
        int x = (t >= off) ? tsum[t-off] : 0;
        __syncthreads();
        tsum[t] += x;
        __syncthreads();
    }
    int run = tsum[t] - s;
    if (idx0+0 < n) out[idx0+0] = run; run += v0;
    if (idx0+1 < n) out[idx0+1] = run; run += v1;
    if (idx0+2 < n) out[idx0+2] = run; run += v2;
    if (idx0+3 < n) out[idx0+3] = run;
    if (bsums && t == 255) bsums[blockIdx.x] = tsum[255];
}

__global__ void scan_add_kernel(int* __restrict__ out, const int* __restrict__ bs,
                                int n, int total) {
    int i = blockIdx.x*blockDim.x + threadIdx.x;
    if (i < n) out[i] += bs[i >> 10];
    if (i == 0) out[n] = total;
}

// slot = atomicAdd(&offsets[bin],1): offsets mutates into shifted-by-one bounds.
// Threads 0..3 also zero the 4-entry pad after slot_src[E] (enables unclamped batch-4 reads).
__global__ void fill_kernel(const int* __restrict__ src, const int* __restrict__ dst,
                            const int* __restrict__ et, int* __restrict__ offsets,
                            int* __restrict__ slot_src, int E, int R) {
    int e = blockIdx.x*blockDim.x + threadIdx.x;
    if (e >= E) return;
    if (e < 4) slot_src[E + e] = 0;
    int bin = dst[e]*R + et[e];
    int slot = atomicAdd(&offsets[bin], 1);
    slot_src[slot] = src[e];
}

// x (f32) -> compact bf16 buffer Xb [N][128] (u32 pairs)
__global__ __launch_bounds__(256)
void xb_kernel(const float* __restrict__ x, unsigned int* __restrict__ Xb2, int N) {
    int t = blockIdx.x*blockDim.x + threadIdx.x;
    int n = t >> 6;
    if (n >= N) return;
    int l = t & 63;
    float2 v = reinterpret_cast<const float2*>(x + (size_t)n*128)[l];
    Xb2[(size_t)n*64 + l] = packbf(v.x, v.y);
}

// 4 waves per node, 2 bins per wave. Bounds shifted-by-one: bin b = [off[b-1], off[b]).
// Masked always-4-wide gather, UNCLAMPED (slot_src padded): all slot+row loads of an
// iteration are independent; over-read slots belong to neighbor bins (valid rows) and
// their values are zero-masked before accumulation.
__global__ __launch_bounds__(256)
void aggregate_kernel(const int* __restrict__ offsets, const int* __restrict__ slot_src,
                      const unsigned int* __restrict__ Xb2, unsigned int* __restrict__ Mc2,
                      int N) {
    int gw = (int)((blockIdx.x*blockDim.x + threadIdx.x) >> 6);
    int node = gw >> 2, part = gw & 3;
    if (node >= N) return;
    int l = threadIdx.x & 63;
    int base = node*8 + part*2;
    int lo   = (base == 0) ? 0 : offsets[base-1];
    int bmid = offsets[base];
    int hi   = offsets[base+1];

    float ax0=0.f, ay0=0.f, ax1=0.f, ay1=0.f;

#define ACC2(E_, U_) { \
    float vx_ = bf2f((unsigned short)((U_) & 0xFFFFu)); \
    float vy_ = bf2f((unsigned short)((U_) >> 16)); \
    if ((E_) < bmid) { ax0 += vx_; ay0 += vy_; } \
    else             { ax1 += vx_; ay1 += vy_; } }

    for (int e = lo; e < hi; e += 4) {
        int s0 = slot_src[e];
        int s1 = slot_src[e+1];
        int s2 = slot_src[e+2];
        int s3 = slot_src[e+3];
        unsigned int u0 = Xb2[(size_t)s0*64 + l];
        unsigned int u1 = Xb2[(size_t)s1*64 + l];
        unsigned int u2 = Xb2[(size_t)s2*64 + l];
        unsigned int u3 = Xb2[(size_t)s3*64 + l];
        if (e+1 >= hi) u1 = 0u;        // wave-uniform masks
        if (e+2 >= hi) u2 = 0u;
        if (e+3 >= hi) u3 = 0u;
        ACC2(e+0, u0) ACC2(e+1, u1) ACC2(e+2, u2) ACC2(e+3, u3)
    }
#undef ACC2

    unsigned int* Mrow = Mc2 + (size_t)node*512;
    float i0 = 1.f/fmaxf((float)(bmid-lo), 1.f);
    float i1 = 1.f/fmaxf((float)(hi-bmid), 1.f);
    __builtin_nontemporal_store(packbf(ax0*i0, ay0*i0), &Mrow[(2*part+0)*64 + l]);
    __builtin_nontemporal_store(packbf(ax1*i1, ay1*i1), &Mrow[(2*part+1)*64 + l]);
}

// h(bf16)[Mpad][128] = relu( [Mc | Xb] @ Bt^T + bias )
// Col-split with XCD-pairing: blk = q*16 + c*8 + m encodes row-block rb=q*8+m and
// col half c; both halves of rb satisfy blk%8==m -> same XCD L2 -> A fetched once.
// Block = 64 rows x 64 cols, BK=64, 16 KB LDS, gload_lds(16B), XOR swizzle (T21).
// 4 waves: rg=wid&1 (32 rows), cg=wid>>1 (32 cols).
__global__ __launch_bounds__(256)
void mfma_gemm_kernel(const unsigned short* __restrict__ Mc,
                      const unsigned short* __restrict__ Xb,
                      const unsigned short* __restrict__ Btc,
                      const float* __restrict__ bias,
                      unsigned short* __restrict__ h, int MBrows) {
    __shared__ char ldsA[64*128];    // 8 KB
    __shared__ char ldsB[64*128];    // 8 KB

    int tid  = threadIdx.x;
    int lane = tid & 63;
    int wid  = tid >> 6;
    int rg = wid & 1, cg = wid >> 1;
    int fr = lane & 15, kb = lane >> 4;

    int blk = blockIdx.x;
    int q = blk >> 4, rem = blk & 15, c = rem >> 3, m = rem & 7;
    int rb = q*8 + m;
    if (rb >= MBrows) return;
    long m0 = (long)rb * 64;
    int colbase = c * 64;

    int lrow8 = lane >> 3;            // 0..7 row within a gload issue
    int lcb   = (lane & 7) * 16;      // 16B slot within 128B row

    f32x4 acc[2][2];
    #pragma unroll
    for (int mf = 0; mf < 2; ++mf)
        #pragma unroll
        for (int nf = 0; nf < 2; ++nf) acc[mf][nf] = f32x4{0.f,0.f,0.f,0.f};

    const char* McB = (const char*)Mc;
    const char* XbB = (const char*)Xb;
    const char* BtB = (const char*)Btc;

    for (int t = 0; t < 18; ++t) {
        #pragma unroll
        for (int i = 0; i < 2; ++i) {
            int row = wid*16 + i*8 + lrow8;
            int sw  = lcb ^ ((row & 7) << 4);
            const char* g = (t < 16)
                ? McB + (size_t)(m0 + row)*2048 + t*128 + sw
                : XbB + (size_t)(m0 + row)*256 + (t-16)*128 + sw;
            gload_lds16(g, &ldsA[wid*2048 + i*1024 + lane*16]);
        }
        #pragma unroll
        for (int i = 0; i < 2; ++i) {
            int col = wid*16 + i*8 + lrow8;       // local col 0..63
            int sw  = lcb ^ ((col & 7) << 4);
            const char* g = BtB + (size_t)(colbase + col)*2304 + t*128 + sw;
            gload_lds16(g, &ldsB[wid*2048 + i*1024 + lane*16]);
        }
        __syncthreads();

        bf16x8 af[2][2], bfr[2][2];
        #pragma unroll
        for (int mf = 0; mf < 2; ++mf) {
            int row = rg*32 + mf*16 + fr;
            #pragma unroll
            for (int kk = 0; kk < 2; ++kk) {
                int byte = row*128 + ((kk*64 + kb*16) ^ ((row & 7) << 4));
                af[mf][kk] = *reinterpret_cast<const bf16x8*>(&ldsA[byte]);
            }
        }
        #pragma unroll
        for (int nf = 0; nf < 2; ++nf) {
            int col = cg*32 + nf*16 + fr;         // local col
            #pragma unroll
            for (int kk = 0; kk < 2; ++kk) {
                int byte = col*128 + ((kk*64 + kb*16) ^ ((col & 7) << 4));
                bfr[nf][kk] = *reinterpret_cast<const bf16x8*>(&ldsB[byte]);
            }
        }
        #pragma unroll
        for (int kk = 0; kk < 2; ++kk)
            #pragma unroll
            for (int mf = 0; mf < 2; ++mf)
                #pragma unroll
                for (int nf = 0; nf < 2; ++nf)
                    acc[mf][nf] = __builtin_amdgcn_mfma_f32_16x16x32_bf16(
                        af[mf][kk], bfr[nf][kk], acc[mf][nf], 0, 0, 0);
        __syncthreads();
    }

    float bb[2];
    #pragma unroll
    for (int nf = 0; nf < 2; ++nf) bb[nf] = bias[colbase + cg*32 + nf*16 + fr];

    #pragma unroll
    for (int mf = 0; mf < 2; ++mf)
        #pragma unroll
        for (int q2 = 0; q2 < 4; ++q2) {
            long r = m0 + rg*32 + mf*16 + kb*4 + q2;
            unsigned short* hr = h + (size_t)r*128 + colbase + cg*32;
            #pragma unroll
            for (int nf = 0; nf < 2; ++nf)
                hr[nf*16 + fr] = f2bf(fmaxf(acc[mf][nf][q2] + bb[nf], 0.f));
        }
}

// Mean-pool partial sums: grid (G, 8), per-graph row range via binary search.
__global__ __launch_bounds__(256)
void pool_kernel(const unsigned int* __restrict__ h2, const int* __restrict__ batch,
                 float* __restrict__ psum, int N) {
    int g = blockIdx.x;
    int t = threadIdx.x;
    int lo = 0, hi = N;
    while (lo < hi) { int mid = (lo+hi) >> 1; if (batch[mid] < g) lo = mid+1; else hi = mid; }
    int s0 = lo;
    hi = N;
    while (lo < hi) { int mid = (lo+hi) >> 1; if (batch[mid] < g+1) lo = mid+1; else hi = mid; }
    int s1 = lo;
    int len = s1 - s0;
    int chunk = blockIdx.y, NC = gridDim.y;
    int a = s0 + (int)((long long)len * chunk / NC);
    int b = s0 + (int)((long long)len * (chunk+1) / NC);

    int d2 = t & 63;
    float ax = 0.f, ay = 0.f;
    for (int row = a + (t >> 6); row < b; row += 4) {
        unsigned int u = h2[(size_t)row*64 + d2];
        ax += bf2f((unsigned short)(u & 0xFFFFu));
        ay += bf2f((unsigned short)(u >> 16));
    }
    atomicAdd(&psum[(size_t)g*128 + 2*d2    ], ax);
    atomicAdd(&psum[(size_t)g*128 + 2*d2 + 1], ay);
}

// out[g][c] = (psum[g]/cnt_g) @ fc_w + fc_b   (G*C threads; cnt via binary search)
__global__ void fc_kernel(const float* __restrict__ psum, const int* __restrict__ batch,
                          const float* __restrict__ fw, const float* __restrict__ fb,
                          float* __restrict__ out, int N, int G, int C) {
    int idx = blockIdx.x*blockDim.x + threadIdx.x;
    if (idx >= G*C) return;
    int g = idx / C, cc = idx - g*C;
    int lo = 0, hi = N;
    while (lo < hi) { int mid = (lo+hi) >> 1; if (batch[mid] < g) lo = mid+1; else hi = mid; }
    int s0 = lo;
    hi = N;
    while (lo < hi) { int mid = (lo+hi) >> 1; if (batch[mid] < g+1) lo = mid+1; else hi = mid; }
    float inv = 1.f / fmaxf((float)(lo - s0), 1.f);
    float s = fb[cc];
    #pragma unroll 4
    for (int k = 0; k < 128; ++k)
        s += psum[(size_t)g*128 + k] * inv * fw[(size_t)k*C + cc];
    out[idx] = s;
}

extern "C" void kernel_launch(void* const* d_in, const int* in_sizes, int n_in,
                              void* d_out, int out_size, void* d_ws, size_t ws_size,
                              hipStream_t stream) {
    const float* x       = (const float*)d_in[0];
    const int*   eindex  = (const int*)  d_in[1];
    const int*   etype   = (const int*)  d_in[2];
    const int*   batch   = (const int*)  d_in[4];
    const float* basis   = (const float*)d_in[6];
    const float* comp    = (const float*)d_in[7];
    const float* root    = (const float*)d_in[8];
    const float* bias    = (const float*)d_in[9];
    const float* fc_w    = (const float*)d_in[10];
    const float* fc_b    = (const float*)d_in[11];

    int N  = in_sizes[4];          // 50000
    int E  = in_sizes[2];          // 600000
    int C  = in_sizes[11];         // 16
    int G  = out_size / C;         // 64
    int IO = in_sizes[8];          // 16384
    int B  = in_sizes[6] / IO;     // 4
    int R  = in_sizes[7] / B;      // 8
    int NR = N * R;
    int MB = ceil_div(N, 64);      // 64-row GEMM row-blocks (782)
    int Mpad = MB * 64;
    int grid_gemm = ceil_div(MB, 8) * 16;   // XCD-paired col-split grid (1568)

    const int* src = eindex;
    const int* dst = eindex + E;

    // ---- workspace layout (~134 MB) ----
    char* base = (char*)d_ws;
    size_t off = 0;
    auto alloc = [&](size_t bytes) -> char* {
        char* p = base + off;
        off = align_up(off + bytes, 256);
        return p;
    };
    unsigned short* Bt  = (unsigned short*)alloc(sizeof(unsigned short)*128*1152);
    int*   cnt      = (int*)  alloc(sizeof(int)*(size_t)NR);
    float* psum     = (float*)alloc(sizeof(float)*(size_t)G*128);   // adjacent to cnt: one memset
    int*   offsets  = (int*)  alloc(sizeof(int)*((size_t)NR+1));
    int*   bsums    = (int*)  alloc(sizeof(int)*1024);
    int*   slot_src = (int*)  alloc(sizeof(int)*((size_t)E+4));
    unsigned short* h  = (unsigned short*)alloc(sizeof(unsigned short)*(size_t)Mpad*128);
    unsigned short* Xb = (unsigned short*)alloc(sizeof(unsigned short)*(size_t)Mpad*128);
    unsigned short* Mc = (unsigned short*)alloc(sizeof(unsigned short)*(size_t)Mpad*1024);

    // ---- pipeline ----
    hipMemsetAsync(cnt, 0, (size_t)((char*)(psum + (size_t)G*128) - (char*)cnt), stream);
    compute_Bt_kernel<<<ceil_div(128*1152,256),256,0,stream>>>(comp, basis, root, Bt, B);
    count_kernel<<<ceil_div(E,256),256,0,stream>>>(dst, etype, cnt, E, R);

    int nb = ceil_div(NR, 1024);
    scan_block_kernel<<<nb,256,0,stream>>>(cnt, offsets, bsums, NR);
    scan_block_kernel<<<1,256,0,stream>>>(bsums, bsums, nullptr, nb);
    scan_add_kernel<<<ceil_div(NR,256),256,0,stream>>>(offsets, bsums, NR, E);

    fill_kernel<<<ceil_div(E,256),256,0,stream>>>(src, dst, etype, offsets, slot_src, E, R);

    xb_kernel<<<ceil_div(N*64,256),256,0,stream>>>(x, (unsigned int*)Xb, N);
    aggregate_kernel<<<ceil_div(N*4*64,256),256,0,stream>>>(offsets, slot_src,
                                                            (const unsigned int*)Xb,
                                                            (unsigned int*)Mc, N);

    mfma_gemm_kernel<<<grid_gemm,256,0,stream>>>(Mc, Xb, Bt, bias, h, MB);

    pool_kernel<<<dim3(G,8),256,0,stream>>>((const unsigned int*)h, batch, psum, N);
    fc_kernel<<<ceil_div(G*C,256),256,0,stream>>>(psum, batch, fc_w, fc_b,
                                                  (float*)d_out, N, G, C);
}

// Round 11
// 209.704 us; speedup vs baseline: 1.2531x; 1.0368x over previous
//
#include <hip/hip_runtime.h>

static inline int ceil_div(int a, int b){ return (a+b-1)/b; }
static inline size_t align_up(size_t x, size_t a){ return (x + a - 1) / a * a; }

typedef __bf16 bf16x8 __attribute__((ext_vector_type(8)));
typedef float  f32x4  __attribute__((ext_vector_type(4)));

static __device__ inline unsigned short f2bf(float f){
    unsigned int u = __float_as_uint(f);
    unsigned int lsb = (u >> 16) & 1u;
    u += 0x7FFFu + lsb;
    return (unsigned short)(u >> 16);
}
static __device__ inline float bf2f(unsigned short b){
    return __uint_as_float(((unsigned int)b) << 16);
}
static __device__ inline unsigned int packbf(float a, float b){
    return (unsigned int)f2bf(a) | ((unsigned int)f2bf(b) << 16);
}

// async 16B global->LDS (wave-uniform LDS base + lane*16 layout)
static __device__ inline void gload_lds16(const void* g, void* l) {
    __builtin_amdgcn_global_load_lds(
        (const __attribute__((address_space(1))) unsigned int*)g,
        (__attribute__((address_space(3))) unsigned int*)l, 16, 0, 0);
}

// Bt[o][kk] bf16: kk<1024 -> W[r=kk>>7][i=kk&127][o]; kk>=1024 -> root[kk-1024][o]
__global__ void compute_Bt_kernel(const float* __restrict__ comp, const float* __restrict__ basis,
                                  const float* __restrict__ root, unsigned short* __restrict__ Bt,
                                  int B) {
    int idx = blockIdx.x*blockDim.x + threadIdx.x;
    if (idx >= 128*1152) return;
    int o = idx / 1152, kk = idx - o*1152;
    float val;
    if (kk < 1024) {
        int r = kk >> 7, i = kk & 127;
        val = 0.f;
        for (int b = 0; b < B; ++b)
            val += comp[r*B+b] * basis[((size_t)b*128 + i)*128 + o];
    } else {
        val = root[(size_t)(kk-1024)*128 + o];
    }
    Bt[idx] = f2bf(val);
}

__global__ void count_kernel(const int* __restrict__ dst, const int* __restrict__ et,
                             int* __restrict__ cnt, int E, int R) {
    int e = blockIdx.x*blockDim.x + threadIdx.x;
    if (e >= E) return;
    atomicAdd(&cnt[(size_t)dst[e]*R + et[e]], 1);
}

__global__ __launch_bounds__(256)
void scan_block_kernel(const int* __restrict__ in, int* __restrict__ out,
                       int* __restrict__ bsums, int n) {
    __shared__ int tsum[256];
    int t = threadIdx.x;
    int idx0 = blockIdx.x*1024 + t*4;
    int v0 = (idx0+0 < n) ? in[idx0+0] : 0;
    int v1 = (idx0+1 < n) ? in[idx0+1] : 0;
    int v2 = (idx0+2 < n) ? in[idx0+2] : 0;
    int v3 = (idx0+3 < n) ? in[idx0+3] : 0;
    int s = v0+v1+v2+v3;
    tsum[t] = s; __syncthreads();
    for (int off = 1; off < 256; off <<= 1) {
        int x = (t >= off) ? tsum[t-off] : 0;
        __syncthreads();
        tsum[t] += x;
        __syncthreads();
    }
    int run = tsum[t] - s;
    if (idx0+0 < n) out[idx0+0] = run; run += v0;
    if (idx0+1 < n) out[idx0+1] = run; run += v1;
    if (idx0+2 < n) out[idx0+2] = run; run += v2;
    if (idx0+3 < n) out[idx0+3] = run;
    if (bsums && t == 255) bsums[blockIdx.x] = tsum[255];
}

__global__ void scan_add_kernel(int* __restrict__ out, const int* __restrict__ bs,
                                int n, int total) {
    int i = blockIdx.x*blockDim.x + threadIdx.x;
    if (i < n) out[i] += bs[i >> 10];
    if (i == 0) out[n] = total;
}

// slot = atomicAdd(&offsets[bin],1): offsets mutates into shifted-by-one bounds.
// slot_off stores PRE-SHIFTED u32 index (src<<6 = row offset in Xb2 units).
// Threads 0..3 zero the 4-entry pad (enables unclamped batch-4 reads).
__global__ void fill_kernel(const int* __restrict__ src, const int* __restrict__ dst,
                            const int* __restrict__ et, int* __restrict__ offsets,
                            int* __restrict__ slot_off, int E, int R) {
    int e = blockIdx.x*blockDim.x + threadIdx.x;
    if (e >= E) return;
    if (e < 4) slot_off[E + e] = 0;
    int bin = dst[e]*R + et[e];
    int slot = atomicAdd(&offsets[bin], 1);
    slot_off[slot] = src[e] << 6;
}

// x (f32) -> compact bf16 buffer Xb [N][128] (u32 pairs)
__global__ __launch_bounds__(256)
void xb_kernel(const float* __restrict__ x, unsigned int* __restrict__ Xb2, int N) {
    int t = blockIdx.x*blockDim.x + threadIdx.x;
    int n = t >> 6;
    if (n >= N) return;
    int l = t & 63;
    float2 v = reinterpret_cast<const float2*>(x + (size_t)n*128)[l];
    Xb2[(size_t)n*64 + l] = packbf(v.x, v.y);
}

// 4 waves per node, 2 bins per wave. Bounds shifted-by-one: bin b = [off[b-1], off[b]).
// SCALARIZED: wave index / bounds / slot offsets / all conditions go through
// readfirstlane -> SALU + s_load + uniform branches; per-edge vector work is
// 1 v_add (addr) + saddr load + 2 unpack + 2 adds.
__global__ __launch_bounds__(256)
void aggregate_kernel(const int* __restrict__ offsets, const int* __restrict__ slot_off,
                      const unsigned int* __restrict__ Xb2, unsigned int* __restrict__ Mc2,
                      int N) {
    int gw = __builtin_amdgcn_readfirstlane((int)((blockIdx.x*blockDim.x + threadIdx.x) >> 6));
    int node = gw >> 2, part = gw & 3;
    if (node >= N) return;
    int l = threadIdx.x & 63;
    int base = node*8 + part*2;
    int lo   = __builtin_amdgcn_readfirstlane((base == 0) ? 0 : offsets[base-1]);
    int bmid = __builtin_amdgcn_readfirstlane(offsets[base]);
    int hi   = __builtin_amdgcn_readfirstlane(offsets[base+1]);

    float ax0=0.f, ay0=0.f, ax1=0.f, ay1=0.f;

#define ACCU(U_, TO0_) { \
    float vx_ = __uint_as_float((U_) << 16); \
    float vy_ = __uint_as_float((U_) & 0xFFFF0000u); \
    if (TO0_) { ax0 += vx_; ay0 += vy_; } else { ax1 += vx_; ay1 += vy_; } }

    for (int e = lo; e < hi; e += 4) {
        int sb0 = __builtin_amdgcn_readfirstlane(slot_off[e]);
        int sb1 = __builtin_amdgcn_readfirstlane(slot_off[e+1]);
        int sb2 = __builtin_amdgcn_readfirstlane(slot_off[e+2]);
        int sb3 = __builtin_amdgcn_readfirstlane(slot_off[e+3]);
        unsigned int u0 = Xb2[(unsigned)(sb0 + l)];
        unsigned int u1 = Xb2[(unsigned)(sb1 + l)];
        unsigned int u2 = Xb2[(unsigned)(sb2 + l)];
        unsigned int u3 = Xb2[(unsigned)(sb3 + l)];
        ACCU(u0, e < bmid)
        if (e+1 < hi) ACCU(u1, e+1 < bmid)
        if (e+2 < hi) ACCU(u2, e+2 < bmid)
        if (e+3 < hi) ACCU(u3, e+3 < bmid)
    }
#undef ACCU

    unsigned int* Mrow = Mc2 + (size_t)node*512;
    float i0 = 1.f/fmaxf((float)(bmid-lo), 1.f);
    float i1 = 1.f/fmaxf((float)(hi-bmid), 1.f);
    Mrow[(2*part+0)*64 + l] = packbf(ax0*i0, ay0*i0);
    Mrow[(2*part+1)*64 + l] = packbf(ax1*i1, ay1*i1);
}

// h(bf16)[Mpad][128] = relu( [Mc | Xb] @ Bt^T + bias )
// Col-split with XCD-pairing: blk = q*16 + c*8 + m encodes row-block rb=q*8+m and
// col half c; both halves of rb satisfy blk%8==m -> same XCD L2 -> A fetched once.
// Block = 64 rows x 64 cols, BK=64, 16 KB LDS, gload_lds(16B), XOR swizzle (T21).
__global__ __launch_bounds__(256)
void mfma_gemm_kernel(const unsigned short* __restrict__ Mc,
                      const unsigned short* __restrict__ Xb,
                      const unsigned short* __restrict__ Btc,
                      const float* __restrict__ bias,
                      unsigned short* __restrict__ h, int MBrows) {
    __shared__ char ldsA[64*128];    // 8 KB
    __shared__ char ldsB[64*128];    // 8 KB

    int tid  = threadIdx.x;
    int lane = tid & 63;
    int wid  = tid >> 6;
    int rg = wid & 1, cg = wid >> 1;
    int fr = lane & 15, kb = lane >> 4;

    int blk = blockIdx.x;
    int q = blk >> 4, rem = blk & 15, c = rem >> 3, m = rem & 7;
    int rb = q*8 + m;
    if (rb >= MBrows) return;
    long m0 = (long)rb * 64;
    int colbase = c * 64;

    int lrow8 = lane >> 3;            // 0..7 row within a gload issue
    int lcb   = (lane & 7) * 16;      // 16B slot within 128B row

    f32x4 acc[2][2];
    #pragma unroll
    for (int mf = 0; mf < 2; ++mf)
        #pragma unroll
        for (int nf = 0; nf < 2; ++nf) acc[mf][nf] = f32x4{0.f,0.f,0.f,0.f};

    const char* McB = (const char*)Mc;
    const char* XbB = (const char*)Xb;
    const char* BtB = (const char*)Btc;

    for (int t = 0; t < 18; ++t) {
        #pragma unroll
        for (int i = 0; i < 2; ++i) {
            int row = wid*16 + i*8 + lrow8;
            int sw  = lcb ^ ((row & 7) << 4);
            const char* g = (t < 16)
                ? McB + (size_t)(m0 + row)*2048 + t*128 + sw
                : XbB + (size_t)(m0 + row)*256 + (t-16)*128 + sw;
            gload_lds16(g, &ldsA[wid*2048 + i*1024 + lane*16]);
        }
        #pragma unroll
        for (int i = 0; i < 2; ++i) {
            int col = wid*16 + i*8 + lrow8;       // local col 0..63
            int sw  = lcb ^ ((col & 7) << 4);
            const char* g = BtB + (size_t)(colbase + col)*2304 + t*128 + sw;
            gload_lds16(g, &ldsB[wid*2048 + i*1024 + lane*16]);
        }
        __syncthreads();

        bf16x8 af[2][2], bfr[2][2];
        #pragma unroll
        for (int mf = 0; mf < 2; ++mf) {
            int row = rg*32 + mf*16 + fr;
            #pragma unroll
            for (int kk = 0; kk < 2; ++kk) {
                int byte = row*128 + ((kk*64 + kb*16) ^ ((row & 7) << 4));
                af[mf][kk] = *reinterpret_cast<const bf16x8*>(&ldsA[byte]);
            }
        }
        #pragma unroll
        for (int nf = 0; nf < 2; ++nf) {
            int col = cg*32 + nf*16 + fr;         // local col
            #pragma unroll
            for (int kk = 0; kk < 2; ++kk) {
                int byte = col*128 + ((kk*64 + kb*16) ^ ((col & 7) << 4));
                bfr[nf][kk] = *reinterpret_cast<const bf16x8*>(&ldsB[byte]);
            }
        }
        #pragma unroll
        for (int kk = 0; kk < 2; ++kk)
            #pragma unroll
            for (int mf = 0; mf < 2; ++mf)
                #pragma unroll
                for (int nf = 0; nf < 2; ++nf)
                    acc[mf][nf] = __builtin_amdgcn_mfma_f32_16x16x32_bf16(
                        af[mf][kk], bfr[nf][kk], acc[mf][nf], 0, 0, 0);
        __syncthreads();
    }

    float bb[2];
    #pragma unroll
    for (int nf = 0; nf < 2; ++nf) bb[nf] = bias[colbase + cg*32 + nf*16 + fr];

    #pragma unroll
    for (int mf = 0; mf < 2; ++mf)
        #pragma unroll
        for (int q2 = 0; q2 < 4; ++q2) {
            long r = m0 + rg*32 + mf*16 + kb*4 + q2;
            unsigned short* hr = h + (size_t)r*128 + colbase + cg*32;
            #pragma unroll
            for (int nf = 0; nf < 2; ++nf)
                hr[nf*16 + fr] = f2bf(fmaxf(acc[mf][nf][q2] + bb[nf], 0.f));
        }
}

// Mean-pool partial sums: grid (G, 8), per-graph row range via binary search.
__global__ __launch_bounds__(256)
void pool_kernel(const unsigned int* __restrict__ h2, const int* __restrict__ batch,
                 float* __restrict__ psum, int N) {
    int g = blockIdx.x;
    int t = threadIdx.x;
    int lo = 0, hi = N;
    while (lo < hi) { int mid = (lo+hi) >> 1; if (batch[mid] < g) lo = mid+1; else hi = mid; }
    int s0 = lo;
    hi = N;
    while (lo < hi) { int mid = (lo+hi) >> 1; if (batch[mid] < g+1) lo = mid+1; else hi = mid; }
    int s1 = lo;
    int len = s1 - s0;
    int chunk = blockIdx.y, NC = gridDim.y;
    int a = s0 + (int)((long long)len * chunk / NC);
    int b = s0 + (int)((long long)len * (chunk+1) / NC);

    int d2 = t & 63;
    float ax = 0.f, ay = 0.f;
    for (int row = a + (t >> 6); row < b; row += 4) {
        unsigned int u = h2[(size_t)row*64 + d2];
        ax += bf2f((unsigned short)(u & 0xFFFFu));
        ay += bf2f((unsigned short)(u >> 16));
    }
    atomicAdd(&psum[(size_t)g*128 + 2*d2    ], ax);
    atomicAdd(&psum[(size_t)g*128 + 2*d2 + 1], ay);
}

// out[g][c] = (psum[g]/cnt_g) @ fc_w + fc_b   (G*C threads; cnt via binary search)
__global__ void fc_kernel(const float* __restrict__ psum, const int* __restrict__ batch,
                          const float* __restrict__ fw, const float* __restrict__ fb,
                          float* __restrict__ out, int N, int G, int C) {
    int idx = blockIdx.x*blockDim.x + threadIdx.x;
    if (idx >= G*C) return;
    int g = idx / C, cc = idx - g*C;
    int lo = 0, hi = N;
    while (lo < hi) { int mid = (lo+hi) >> 1; if (batch[mid] < g) lo = mid+1; else hi = mid; }
    int s0 = lo;
    hi = N;
    while (lo < hi) { int mid = (lo+hi) >> 1; if (batch[mid] < g+1) lo = mid+1; else hi = mid; }
    float inv = 1.f / fmaxf((float)(lo - s0), 1.f);
    float s = fb[cc];
    #pragma unroll 4
    for (int k = 0; k < 128; ++k)
        s += psum[(size_t)g*128 + k] * inv * fw[(size_t)k*C + cc];
    out[idx] = s;
}

extern "C" void kernel_launch(void* const* d_in, const int* in_sizes, int n_in,
                              void* d_out, int out_size, void* d_ws, size_t ws_size,
                              hipStream_t stream) {
    const float* x       = (const float*)d_in[0];
    const int*   eindex  = (const int*)  d_in[1];
    const int*   etype   = (const int*)  d_in[2];
    const int*   batch   = (const int*)  d_in[4];
    const float* basis   = (const float*)d_in[6];
    const float* comp    = (const float*)d_in[7];
    const float* root    = (const float*)d_in[8];
    const float* bias    = (const float*)d_in[9];
    const float* fc_w    = (const float*)d_in[10];
    const float* fc_b    = (const float*)d_in[11];

    int N  = in_sizes[4];          // 50000
    int E  = in_sizes[2];          // 600000
    int C  = in_sizes[11];         // 16
    int G  = out_size / C;         // 64
    int IO = in_sizes[8];          // 16384
    int B  = in_sizes[6] / IO;     // 4
    int R  = in_sizes[7] / B;      // 8
    int NR = N * R;
    int MB = ceil_div(N, 64);      // 64-row GEMM row-blocks (782)
    int Mpad = MB * 64;
    int grid_gemm = ceil_div(MB, 8) * 16;   // XCD-paired col-split grid (1568)

    const int* src = eindex;
    const int* dst = eindex + E;

    // ---- workspace layout (~134 MB) ----
    char* base = (char*)d_ws;
    size_t off = 0;
    auto alloc = [&](size_t bytes) -> char* {
        char* p = base + off;
        off = align_up(off + bytes, 256);
        return p;
    };
    unsigned short* Bt  = (unsigned short*)alloc(sizeof(unsigned short)*128*1152);
    int*   cnt      = (int*)  alloc(sizeof(int)*(size_t)NR);
    float* psum     = (float*)alloc(sizeof(float)*(size_t)G*128);   // adjacent to cnt: one memset
    int*   offsets  = (int*)  alloc(sizeof(int)*((size_t)NR+1));
    int*   bsums    = (int*)  alloc(sizeof(int)*1024);
    int*   slot_off = (int*)  alloc(sizeof(int)*((size_t)E+4));
    unsigned short* h  = (unsigned short*)alloc(sizeof(unsigned short)*(size_t)Mpad*128);
    unsigned short* Xb = (unsigned short*)alloc(sizeof(unsigned short)*(size_t)Mpad*128);
    unsigned short* Mc = (unsigned short*)alloc(sizeof(unsigned short)*(size_t)Mpad*1024);

    // ---- pipeline ----
    hipMemsetAsync(cnt, 0, (size_t)((char*)(psum + (size_t)G*128) - (char*)cnt), stream);
    compute_Bt_kernel<<<ceil_div(128*1152,256),256,0,stream>>>(comp, basis, root, Bt, B);
    count_kernel<<<ceil_div(E,256),256,0,stream>>>(dst, etype, cnt, E, R);

    int nb = ceil_div(NR, 1024);
    scan_block_kernel<<<nb,256,0,stream>>>(cnt, offsets, bsums, NR);
    scan_block_kernel<<<1,256,0,stream>>>(bsums, bsums, nullptr, nb);
    scan_add_kernel<<<ceil_div(NR,256),256,0,stream>>>(offsets, bsums, NR, E);

    fill_kernel<<<ceil_div(E,256),256,0,stream>>>(src, dst, etype, offsets, slot_off, E, R);

    xb_kernel<<<ceil_div(N*64,256),256,0,stream>>>(x, (unsigned int*)Xb, N);
    aggregate_kernel<<<ceil_div(N*4*64,256),256,0,stream>>>(offsets, slot_off,
                                                            (const unsigned int*)Xb,
                                                            (unsigned int*)Mc, N);

    mfma_gemm_kernel<<<grid_gemm,256,0,stream>>>(Mc, Xb, Bt, bias, h, MB);

    pool_kernel<<<dim3(G,8),256,0,stream>>>((const unsigned int*)h, batch, psum, N);
    fc_kernel<<<ceil_div(G*C,256),256,0,stream>>>(psum, batch, fc_w, fc_b,
                                                  (float*)d_out, N, G, C);
}